// Round 10
// baseline (86.307 us; speedup 1.0000x reference)
//
#include <hip/hip_runtime.h>
#include <math.h>

#define DIM 64
#define NE 4
#define B_SZ 4
#define NQ 4096
#define NK 4096

#define WBLOCKS 256                         // writer blocks: 1 per CU
#define CPB 8                               // chunks per block per iteration
#define TOTAL_CHUNKS (B_SZ * NQ * 4)        // 65536 chunks of 1024 floats (4 KB)
#define ITERS (TOTAL_CHUNKS / (WBLOCKS * CPB))   // 32

typedef float fvec4 __attribute__((ext_vector_type(4)));

// ---------------------------------------------------------------------------
// Kernel 1: per-row features, THREAD-per-row. (R5 verbatim)
// ---------------------------------------------------------------------------
__global__ __launch_bounds__(256) void feat_kernel(
    const float* __restrict__ queries,
    const float* __restrict__ keys,
    const float* __restrict__ center,
    const float* __restrict__ outer_radius,
    const float* __restrict__ hole_radius,
    const float* __restrict__ entry_points,
    const float* __restrict__ entry_strengths,
    const float* __restrict__ amplitude,
    float* __restrict__ qf,   // [B][5][NQ]
    float* __restrict__ kf)   // [B][5][NK]
{
    const int row = blockIdx.x * blockDim.x + threadIdx.x;   // 0..32767
    const int nqrows = B_SZ * NQ;
    const bool is_q = row < nqrows;
    const int  r    = is_q ? row : row - nqrows;             // 0..16383
    const float* src = (is_q ? queries : keys) + (size_t)r * DIM;

    float a0 = 0.f, a1 = 0.f, a2 = 0.f, a3 = 0.f, a4 = 0.f;

    #pragma unroll
    for (int j = 0; j < DIM / 4; ++j) {
        const fvec4 v  = *reinterpret_cast<const fvec4*>(src + j * 4);
        const fvec4 c  = *reinterpret_cast<const fvec4*>(center + j * 4);
        const fvec4 p0 = *reinterpret_cast<const fvec4*>(entry_points + 0 * DIM + j * 4);
        const fvec4 p1 = *reinterpret_cast<const fvec4*>(entry_points + 1 * DIM + j * 4);
        const fvec4 p2 = *reinterpret_cast<const fvec4*>(entry_points + 2 * DIM + j * 4);
        const fvec4 p3 = *reinterpret_cast<const fvec4*>(entry_points + 3 * DIM + j * 4);
        #pragma unroll
        for (int cc = 0; cc < 4; ++cc) {
            const float x  = v[cc];
            const float d0 = x - c[cc];
            const float d1 = x - p0[cc];
            const float d2 = x - p1[cc];
            const float d3 = x - p2[cc];
            const float d4 = x - p3[cc];
            a0 += d0 * d0;
            a1 += d1 * d1;
            a2 += d2 * d2;
            a3 += d3 * d3;
            a4 += d4 * d4;
        }
    }

    const float outer_r    = fabsf(outer_radius[0]) + 1e-8f;
    const float hole_r     = fabsf(hole_radius[0]);
    const float hole_ratio = hole_r / outer_r;
    const float amp        = amplitude[0];

    const float dist  = sqrtf(a0);
    const float major = fabsf(dist - outer_r);
    const float torus = fabsf(sqrtf(major * major + hole_r * hole_r) - hole_r);
    const float surf  = (hole_ratio < 0.1f) ? major : torus;

    const float f0 = expf(-0.5f * surf * surf);
    const float f1 = expf(-0.5f * a1);
    const float f2 = expf(-0.5f * a2);
    const float f3 = expf(-0.5f * a3);
    const float f4 = expf(-0.5f * a4);

    const int b = r >> 12;          // r / 4096
    const int n = r & (NQ - 1);     // r % 4096

    if (is_q) {
        float* dst = qf + ((size_t)b * 5) * NQ + n;
        dst[0 * NQ] = amp * f0;
        dst[1 * NQ] = amp * f1;
        dst[2 * NQ] = amp * f2;
        dst[3 * NQ] = amp * f3;
        dst[4 * NQ] = amp * f4;
    } else {
        float w[NE];
        #pragma unroll
        for (int e = 0; e < NE; ++e) {
            float s = 1.0f / (1.0f + expf(-entry_strengths[e]));
            w[e] = (s > 0.1f) ? s : 0.0f;
        }
        float* dst = kf + ((size_t)b * 5) * NK + n;
        dst[0 * NK] = f0;
        dst[1 * NK] = w[0] * f1;
        dst[2 * NK] = w[1] * f2;
        dst[3 * NK] = w[2] * f3;
        dst[4 * NK] = w[3] * f4;
    }
}

// ---------------------------------------------------------------------------
// Kernel 2: cohort-sweep writer with full store ILP.
// Same grid as R9 (256 blocks x 256 threads); only the chunk->address map
// changes. Iteration i: block bid writes 8 consecutive 4 KB chunks at
// c = i*(256*8) + bid*8 + j. The whole cohort's in-flight stores live in
// one sweeping 8 MB window (fillBuffer-like DRAM row locality), and the
// 8 chunk-units per iteration are fully independent (8 outstanding fvec4
// stores per thread, no loop-carried deps — R7's mistake avoided).
// ---------------------------------------------------------------------------
__global__ __launch_bounds__(256) void write_kernel(
    const float* __restrict__ qf,
    const float* __restrict__ kf,
    float* __restrict__ out)
{
    const int tid = threadIdx.x;
    const int bid = blockIdx.x;

    for (int i = 0; i < ITERS; ++i) {
        const int cbase = i * (WBLOCKS * CPB) + bid * CPB;

        #pragma unroll
        for (int j = 0; j < CPB; ++j) {
            const int c  = cbase + j;
            const int cg = c & 3;                 // col-group within row
            const int q  = (c >> 2) & (NQ - 1);   // row
            const int b  = c >> 14;               // batch

            const float* qfb = qf + ((size_t)b * 5) * NQ + q;
            const float q0 = qfb[0 * NQ];
            const float q1 = qfb[1 * NQ];
            const float q2 = qfb[2 * NQ];
            const float q3 = qfb[3 * NQ];
            const float q4 = qfb[4 * NQ];

            const float* kfb = kf + ((size_t)b * 5) * NK + cg * 1024 + tid * 4;

            fvec4 v = q0 * *reinterpret_cast<const fvec4*>(kfb + 0 * (size_t)NK)
                    + q1 * *reinterpret_cast<const fvec4*>(kfb + 1 * (size_t)NK)
                    + q2 * *reinterpret_cast<const fvec4*>(kfb + 2 * (size_t)NK)
                    + q3 * *reinterpret_cast<const fvec4*>(kfb + 3 * (size_t)NK)
                    + q4 * *reinterpret_cast<const fvec4*>(kfb + 4 * (size_t)NK);

            *reinterpret_cast<fvec4*>(out + ((size_t)c << 10) + tid * 4) = v;
        }
    }
}

extern "C" void kernel_launch(void* const* d_in, const int* in_sizes, int n_in,
                              void* d_out, int out_size, void* d_ws, size_t ws_size,
                              hipStream_t stream) {
    const float* queries         = (const float*)d_in[0];
    const float* keys            = (const float*)d_in[1];
    const float* center          = (const float*)d_in[2];
    const float* outer_radius    = (const float*)d_in[3];
    const float* hole_radius     = (const float*)d_in[4];
    const float* entry_points    = (const float*)d_in[5];
    const float* entry_strengths = (const float*)d_in[6];
    const float* amplitude       = (const float*)d_in[7];

    float* qf = (float*)d_ws;                              // B*5*NQ floats
    float* kf = qf + (size_t)B_SZ * 5 * NQ;                // B*5*NK floats
    float* out = (float*)d_out;

    // Kernel 1: 32768 rows, 1 thread/row -> 128 blocks of 256
    {
        const int total_rows = B_SZ * NQ + B_SZ * NK;
        feat_kernel<<<total_rows / 256, 256, 0, stream>>>(
            queries, keys, center, outer_radius, hole_radius,
            entry_points, entry_strengths, amplitude, qf, kf);
    }

    // Kernel 2: cohort-sweep writer, 256 blocks of 256
    {
        write_kernel<<<WBLOCKS, 256, 0, stream>>>(qf, kf, out);
    }
}

// Round 11
// 53.982 us; speedup vs baseline: 1.5988x; 1.5988x over previous
//
#include <hip/hip_runtime.h>
#include <math.h>

#define DIM 64
#define NE 4
#define B_SZ 4
#define NQ 4096
#define NK 4096
#define BQ 8      // q-rows per writer block

typedef float fvec4 __attribute__((ext_vector_type(4)));

// ---------------------------------------------------------------------------
// Kernel 1: per-row features, THREAD-per-row (no shuffles, no lane-0 tail).
// Each thread reads its 64-dim row as 16 fvec4, accumulates 5 squared
// distances, computes 5 expf in-lane, stores coalesced.
//   qf[e=0] = amp * exp(-0.5*surf(q)^2)        kf[e=0] = exp(-0.5*surf(k)^2)
//   qf[e>0] = amp * exp(-0.5*||q-p_e||^2)      kf[e>0] = w_e * exp(-0.5*||k-p_e||^2)
// ---------------------------------------------------------------------------
__global__ __launch_bounds__(256) void feat_kernel(
    const float* __restrict__ queries,
    const float* __restrict__ keys,
    const float* __restrict__ center,
    const float* __restrict__ outer_radius,
    const float* __restrict__ hole_radius,
    const float* __restrict__ entry_points,
    const float* __restrict__ entry_strengths,
    const float* __restrict__ amplitude,
    float* __restrict__ qf,   // [B][5][NQ]
    float* __restrict__ kf)   // [B][5][NK]
{
    const int row = blockIdx.x * blockDim.x + threadIdx.x;   // 0..32767
    const int nqrows = B_SZ * NQ;
    const bool is_q = row < nqrows;
    const int  r    = is_q ? row : row - nqrows;             // 0..16383
    const float* src = (is_q ? queries : keys) + (size_t)r * DIM;

    float a0 = 0.f, a1 = 0.f, a2 = 0.f, a3 = 0.f, a4 = 0.f;

    #pragma unroll
    for (int j = 0; j < DIM / 4; ++j) {
        const fvec4 v  = *reinterpret_cast<const fvec4*>(src + j * 4);
        const fvec4 c  = *reinterpret_cast<const fvec4*>(center + j * 4);
        const fvec4 p0 = *reinterpret_cast<const fvec4*>(entry_points + 0 * DIM + j * 4);
        const fvec4 p1 = *reinterpret_cast<const fvec4*>(entry_points + 1 * DIM + j * 4);
        const fvec4 p2 = *reinterpret_cast<const fvec4*>(entry_points + 2 * DIM + j * 4);
        const fvec4 p3 = *reinterpret_cast<const fvec4*>(entry_points + 3 * DIM + j * 4);
        #pragma unroll
        for (int cc = 0; cc < 4; ++cc) {
            const float x  = v[cc];
            const float d0 = x - c[cc];
            const float d1 = x - p0[cc];
            const float d2 = x - p1[cc];
            const float d3 = x - p2[cc];
            const float d4 = x - p3[cc];
            a0 += d0 * d0;
            a1 += d1 * d1;
            a2 += d2 * d2;
            a3 += d3 * d3;
            a4 += d4 * d4;
        }
    }

    const float outer_r    = fabsf(outer_radius[0]) + 1e-8f;
    const float hole_r     = fabsf(hole_radius[0]);
    const float hole_ratio = hole_r / outer_r;
    const float amp        = amplitude[0];

    const float dist  = sqrtf(a0);
    const float major = fabsf(dist - outer_r);
    const float torus = fabsf(sqrtf(major * major + hole_r * hole_r) - hole_r);
    const float surf  = (hole_ratio < 0.1f) ? major : torus;

    const float f0 = expf(-0.5f * surf * surf);
    const float f1 = expf(-0.5f * a1);
    const float f2 = expf(-0.5f * a2);
    const float f3 = expf(-0.5f * a3);
    const float f4 = expf(-0.5f * a4);

    const int b = r >> 12;          // r / 4096
    const int n = r & (NQ - 1);     // r % 4096

    if (is_q) {
        float* dst = qf + ((size_t)b * 5) * NQ + n;
        dst[0 * NQ] = amp * f0;
        dst[1 * NQ] = amp * f1;
        dst[2 * NQ] = amp * f2;
        dst[3 * NQ] = amp * f3;
        dst[4 * NQ] = amp * f4;
    } else {
        float w[NE];
        #pragma unroll
        for (int e = 0; e < NE; ++e) {
            float s = 1.0f / (1.0f + expf(-entry_strengths[e]));
            w[e] = (s > 0.1f) ? s : 0.0f;
        }
        float* dst = kf + ((size_t)b * 5) * NK + n;
        dst[0 * NK] = f0;
        dst[1 * NK] = w[0] * f1;
        dst[2 * NK] = w[1] * f2;
        dst[3 * NK] = w[2] * f3;
        dst[4 * NK] = w[3] * f4;
    }
}

// ---------------------------------------------------------------------------
// Kernel 2: streaming writer (R5 verbatim — best measured: 54.07 us).
// Block = 256 threads owns BQ=8 rows x ALL 4096 cols (4 column-groups,
// cg-outer). 32 independent fvec4 stores per thread.
// ---------------------------------------------------------------------------
__global__ __launch_bounds__(256) void write_kernel(
    const float* __restrict__ qf,
    const float* __restrict__ kf,
    float* __restrict__ out)
{
    const int b   = blockIdx.y;
    const int q0  = blockIdx.x * BQ;
    const int tid = threadIdx.x;

    const float* qfb = qf + ((size_t)b * 5) * NQ + q0;
    const float* kfb = kf + ((size_t)b * 5) * NK;

    float qv[5][BQ];
    #pragma unroll
    for (int e = 0; e < 5; ++e) {
        fvec4 lo = *reinterpret_cast<const fvec4*>(qfb + (size_t)e * NQ);
        fvec4 hi = *reinterpret_cast<const fvec4*>(qfb + (size_t)e * NQ + 4);
        qv[e][0] = lo.x; qv[e][1] = lo.y; qv[e][2] = lo.z; qv[e][3] = lo.w;
        qv[e][4] = hi.x; qv[e][5] = hi.y; qv[e][6] = hi.z; qv[e][7] = hi.w;
    }

    float* ob = out + ((size_t)(b * NQ + q0)) * NK;

    #pragma unroll
    for (int cg = 0; cg < NK / 1024; ++cg) {
        const int k0 = cg * 1024 + tid * 4;
        fvec4 kc[5];
        #pragma unroll
        for (int e = 0; e < 5; ++e)
            kc[e] = *reinterpret_cast<const fvec4*>(kfb + (size_t)e * NK + k0);

        #pragma unroll
        for (int r = 0; r < BQ; ++r) {
            fvec4 v = qv[0][r] * kc[0] + qv[1][r] * kc[1] + qv[2][r] * kc[2]
                    + qv[3][r] * kc[3] + qv[4][r] * kc[4];
            *reinterpret_cast<fvec4*>(ob + (size_t)r * NK + k0) = v;
        }
    }
}

extern "C" void kernel_launch(void* const* d_in, const int* in_sizes, int n_in,
                              void* d_out, int out_size, void* d_ws, size_t ws_size,
                              hipStream_t stream) {
    const float* queries         = (const float*)d_in[0];
    const float* keys            = (const float*)d_in[1];
    const float* center          = (const float*)d_in[2];
    const float* outer_radius    = (const float*)d_in[3];
    const float* hole_radius     = (const float*)d_in[4];
    const float* entry_points    = (const float*)d_in[5];
    const float* entry_strengths = (const float*)d_in[6];
    const float* amplitude       = (const float*)d_in[7];

    float* qf = (float*)d_ws;                              // B*5*NQ floats
    float* kf = qf + (size_t)B_SZ * 5 * NQ;                // B*5*NK floats
    float* out = (float*)d_out;

    // Kernel 1: 32768 rows, 1 thread/row -> 128 blocks of 256
    {
        const int total_rows = B_SZ * NQ + B_SZ * NK;
        feat_kernel<<<total_rows / 256, 256, 0, stream>>>(
            queries, keys, center, outer_radius, hole_radius,
            entry_points, entry_strengths, amplitude, qf, kf);
    }

    // Kernel 2: (NQ/BQ, B) = (512, 4) blocks of 256
    {
        dim3 grid(NQ / BQ, B_SZ);
        write_kernel<<<grid, 256, 0, stream>>>(qf, kf, out);
    }
}